// Round 6
// baseline (14222.520 us; speedup 1.0000x reference)
//
#include <hip/hip_runtime.h>

#define TT 4096
#define BATCH 128
#define HID 64
#define CK 32              // chunk size
#define NCH (TT / CK)      // 128 chunks
#define NSLOT (NCH + 1)    // 129 checkpoint slots per (dir,b)

__device__ __forceinline__ float sigm(float x) { return 1.f / (1.f + expf(-x)); }
__device__ __forceinline__ float tanh_f(float x) { float e = expf(2.f * x); return 1.f - 2.f / (e + 1.f); }

// ---------------- Kernel A: layer-0 pass, 2 threads/row, store (h,c) ckpt every CK steps ----------------
__global__ __launch_bounds__(512, 2) void lstm_ckpt(
    const float* __restrict__ x,      // [B][T][2]
    const float* __restrict__ w_ih,   // [2][256][2]
    const float* __restrict__ w_hh,   // [2][256][64]
    const float* __restrict__ b_ih, const float* __restrict__ b_hh,
    float* __restrict__ ckpt)         // [2][B][NSLOT][128] (h:0..63, c:64..127)
{
    const int blk = blockIdx.x;
    const int dir = blk & 1;
    const int b   = blk >> 1;
    const int tid = threadIdx.x;
    const int row = tid >> 1, half = tid & 1;

    __shared__ __align__(16) float xs[TT * 2];
    __shared__ __align__(16) float h_lds[HID];
    __shared__ __align__(16) float g_lds[256];

    {   // stage x[b] (32 KB)
        const float4* src = (const float4*)(x + (size_t)b * TT * 2);
        float4* dst = (float4*)xs;
        for (int rr = tid; rr < 2048; rr += 512) dst[rr] = src[rr];
    }
    const int grow = dir * 256 + row;
    float wv[32];
    {
        const float4* wr = (const float4*)(w_hh + (size_t)grow * 64) + half * 8;
        #pragma unroll
        for (int k = 0; k < 8; ++k) {
            float4 v = wr[k];
            wv[4*k] = v.x; wv[4*k+1] = v.y; wv[4*k+2] = v.z; wv[4*k+3] = v.w;
        }
    }
    const float wx0 = half ? 0.f : w_ih[grow * 2 + 0];
    const float wx1 = half ? 0.f : w_ih[grow * 2 + 1];
    const float bias = half ? 0.f : (b_ih[grow] + b_hh[grow]);
    const int gtype = row >> 6;
    float c = 0.f, hreg = 0.f;
    if (tid < HID) h_lds[tid] = 0.f;
    __syncthreads();

    for (int t = 0; t < TT; ++t) {
        const int tt = dir ? (TT - 1 - t) : t;
        if (tid < HID) {   // state BEFORE processing tt
            const int bnum = dir ? (tt + 1) : tt;
            if ((bnum & (CK - 1)) == 0) {
                float* cp = ckpt + (((size_t)(dir * BATCH + b) * NSLOT + (bnum >> 5)) << 7);
                cp[tid] = hreg; cp[HID + tid] = c;
            }
        }
        const float4* h4 = (const float4*)h_lds + half * 8;
        float a0 = 0.f, a1 = 0.f, a2 = 0.f, a3 = 0.f;
        #pragma unroll
        for (int k = 0; k < 8; ++k) {
            float4 hv = h4[k];
            a0 = fmaf(wv[4*k],   hv.x, a0);
            a1 = fmaf(wv[4*k+1], hv.y, a1);
            a2 = fmaf(wv[4*k+2], hv.z, a2);
            a3 = fmaf(wv[4*k+3], hv.w, a3);
        }
        float tot = (a0 + a1) + (a2 + a3);
        tot += __shfl_xor(tot, 1);
        if (half == 0) {
            const float acc = tot + bias + wx0 * xs[tt * 2] + wx1 * xs[tt * 2 + 1];
            g_lds[row] = (gtype == 2) ? tanh_f(acc) : sigm(acc);
        }
        __syncthreads();
        if (tid < HID) {
            const float iv = g_lds[tid], fv = g_lds[64 + tid], gg = g_lds[128 + tid], ov = g_lds[192 + tid];
            c = fv * c + iv * gg;
            hreg = ov * tanh_f(c);
            h_lds[tid] = hreg;
        }
        __syncthreads();
    }
}

// ---------------- Kernel B: fused L1 + GEMM + L0 recompute + logits; 256 threads, all roles stacked ----
// Thread t: L1 gate row t (wl1[64]); L0 rows (dg=t>>7, j=t&127) and (j+128) same dir (wl0[128]);
//           GEMM col t (acc[32], streamed wi1 row t). Updates: t<64 h1; t<128 L0 (du,eu);
//           t in [128,192) logits (wave 2); t in [192,208) x prefetch.
// __launch_bounds__(256, 1): budget 512 VGPR -> allocator lands ~256 (its half-budget habit).
__global__ __launch_bounds__(256, 1) void lstm_fused1(
    const float* __restrict__ x,
    const float* __restrict__ w_ih0, const float* __restrict__ w_hh0,
    const float* __restrict__ b_ih0, const float* __restrict__ b_hh0,
    const float* __restrict__ w_ih1, const float* __restrict__ w_hh1,
    const float* __restrict__ b_ih1, const float* __restrict__ b_hh1,
    const float* __restrict__ fc_w,  const float* __restrict__ ckpt,
    float* __restrict__ plog)        // [2][B][T][2]
{
    const int blk = blockIdx.x;
    const int l1dir = blk & 1;
    const int b = blk >> 1;
    const int tid = threadIdx.x;

    __shared__ __align__(16) float h0buf[2][CK][128];   // 32 KB
    __shared__ __align__(16) float xg1[2][CK][256];     // 64 KB
    __shared__ __align__(16) float xbuf[2][CK][2];
    __shared__ __align__(16) float g1[256];
    __shared__ __align__(16) float g0[2][256];
    __shared__ __align__(16) float h1b[2][HID];
    __shared__ __align__(16) float h0s[2][HID];

    const int dg = tid >> 7;        // L0 dot dir
    const int j  = tid & 127;       // L0 row-pair base
    const int du = tid >> 6;        // L0 update dir (tid<128)
    const int eu = tid & 63;

    float wl1[64];                  // w_hh1 row tid
    float wl0[128];                 // w_hh0 rows (dg,j) and (dg,j+128)
    float acc[32];                  // GEMM accumulators
    float4 wc;                      // streamed wi1 k-chunk
    float biasL1, biasA, biasB, wxA0, wxA1, wxB0, wxB1;
    float fw0 = 0.f, fw1 = 0.f;
    float c1 = 0.f, c0 = 0.f, ckh = 0.f, ckc = 0.f;
    const float4* wip4 = (const float4*)(w_ih1 + (size_t)(l1dir * 256 + tid) * 128);

    {   // L1 weights
        const int grow = l1dir * 256 + tid;
        const float4* wr = (const float4*)(w_hh1 + (size_t)grow * 64);
        #pragma unroll
        for (int k = 0; k < 16; ++k) {
            float4 v = wr[k];
            wl1[4*k] = v.x; wl1[4*k+1] = v.y; wl1[4*k+2] = v.z; wl1[4*k+3] = v.w;
        }
        biasL1 = b_ih1[grow] + b_hh1[grow];
    }
    {   // L0 weights (two rows, same dir)
        const int rA = dg * 256 + j;
        const int rB = rA + 128;
        const float4* wa = (const float4*)(w_hh0 + (size_t)rA * 64);
        const float4* wb = (const float4*)(w_hh0 + (size_t)rB * 64);
        #pragma unroll
        for (int k = 0; k < 16; ++k) {
            float4 v = wa[k];
            wl0[4*k] = v.x; wl0[4*k+1] = v.y; wl0[4*k+2] = v.z; wl0[4*k+3] = v.w;
        }
        #pragma unroll
        for (int k = 0; k < 16; ++k) {
            float4 v = wb[k];
            wl0[64+4*k] = v.x; wl0[64+4*k+1] = v.y; wl0[64+4*k+2] = v.z; wl0[64+4*k+3] = v.w;
        }
        wxA0 = w_ih0[rA * 2 + 0]; wxA1 = w_ih0[rA * 2 + 1];
        wxB0 = w_ih0[rB * 2 + 0]; wxB1 = w_ih0[rB * 2 + 1];
        biasA = b_ih0[rA] + b_hh0[rA];
        biasB = b_ih0[rB] + b_hh0[rB];
    }
    #pragma unroll
    for (int k = 0; k < 32; ++k) acc[k] = 0.f;
    wc = wip4[0];
    if (tid >= 128 && tid < 192) {
        fw0 = fc_w[l1dir * 64 + (tid - 128)];
        fw1 = fc_w[128 + l1dir * 64 + (tid - 128)];
    }

    // init: h1 zero, chunk-0 x, chunk-0 ckpt state
    if (tid < HID) { h1b[0][tid] = 0.f; h1b[1][tid] = 0.f; }
    {
        const int ac0 = l1dir ? (NCH - 1) : 0;
        if (tid < 16)
            ((float4*)xbuf[0])[tid] = ((const float4*)(x + ((size_t)b * TT + (size_t)ac0 * CK) * 2))[tid];
        if (tid < 128) {
            const int slot = du ? (ac0 + 1) : ac0;
            const float* cp = ckpt + (((size_t)(du * BATCH + b) * NSLOT + slot) << 7);
            h0s[du][eu] = cp[eu];
            c0 = cp[HID + eu];
        }
    }
    __syncthreads();

    // phase i: L1 consumes chunk i; GEMM builds xg1 for i+1 from h0buf[(i+1)&1];
    //          L0 computes chunk i+2 into h0buf[i&1]; prefetch ckpt/x for chunk i+3.
    for (int i = -2; i < NCH; ++i) {
        const bool l1act = i >= 0;
        const bool gact  = (i + 1 >= 0) && (i + 1 < NCH);
        const bool l0act = (i + 2) < NCH;
        const int hbL0 = i & 1;
        const int hbG  = (i + 1) & 1;
        for (int s = 0; s < CK; ++s) {
            // ======== phase A ========
            if (s == 0 && (i + 3) < NCH) {
                const int acn = l1dir ? (NCH - 1 - (i + 3)) : (i + 3);
                if (tid < 128) {
                    const int slot = du ? (acn + 1) : acn;
                    const float* cp = ckpt + (((size_t)(du * BATCH + b) * NSLOT + slot) << 7);
                    ckh = cp[eu]; ckc = cp[HID + eu];
                }
                if (tid >= 192 && tid < 208)   // direct x prefetch into other half (consumer 1.5 chunks away)
                    ((float4*)xbuf[(i + 1) & 1])[tid - 192] =
                        ((const float4*)(x + ((size_t)b * TT + (size_t)acn * CK) * 2))[tid - 192];
            }
            if (gact) {   // GEMM: k-chunk s of chunk i+1
                float4 wn = wip4[(s + 1) & (CK - 1)];
                const float4* hb = (const float4*)&h0buf[hbG][0][0] + s;   // row stride 32 float4
                #pragma unroll
                for (int s2 = 0; s2 < 32; ++s2) {
                    float4 hv = hb[s2 * 32];
                    float t0 = acc[s2];
                    t0 = fmaf(wc.x, hv.x, t0);
                    t0 = fmaf(wc.y, hv.y, t0);
                    t0 = fmaf(wc.z, hv.z, t0);
                    t0 = fmaf(wc.w, hv.w, t0);
                    acc[s2] = t0;
                }
                if (s == CK - 1) {
                    #pragma unroll
                    for (int s2 = 0; s2 < 32; ++s2) { xg1[hbG][s2][tid] = acc[s2]; acc[s2] = 0.f; }
                }
                wc = wn;
            }
            if (l0act) {  // L0: two rows, shared h broadcast
                const int orow = dg ? (CK - 1 - s) : s;
                const float4* h4 = (const float4*)h0s[dg];
                float a0 = 0.f, a1 = 0.f, a2 = 0.f, a3 = 0.f;
                float e0 = 0.f, e1 = 0.f, e2 = 0.f, e3 = 0.f;
                #pragma unroll
                for (int k = 0; k < 16; ++k) {
                    float4 hv = h4[k];
                    a0 = fmaf(wl0[4*k],   hv.x, a0);
                    a1 = fmaf(wl0[4*k+1], hv.y, a1);
                    a2 = fmaf(wl0[4*k+2], hv.z, a2);
                    a3 = fmaf(wl0[4*k+3], hv.w, a3);
                    e0 = fmaf(wl0[64+4*k],   hv.x, e0);
                    e1 = fmaf(wl0[64+4*k+1], hv.y, e1);
                    e2 = fmaf(wl0[64+4*k+2], hv.z, e2);
                    e3 = fmaf(wl0[64+4*k+3], hv.w, e3);
                }
                const float xv0 = xbuf[i & 1][orow][0], xv1 = xbuf[i & 1][orow][1];
                const float accA = biasA + ((a0 + a1) + (a2 + a3)) + wxA0 * xv0 + wxA1 * xv1;
                const float accB = biasB + ((e0 + e1) + (e2 + e3)) + wxB0 * xv0 + wxB1 * xv1;
                g0[dg][j]       = sigm(accA);                          // rows 0..127: i,f
                g0[dg][j + 128] = (j < 64) ? tanh_f(accB) : sigm(accB);// g rows tanh, o rows sigm
            }
            if (l1act) {  // L1 dot + logits
                const int u = i * CK + s;
                const float4* h14 = (const float4*)h1b[u & 1];
                float a0 = 0.f, a1 = 0.f, a2 = 0.f, a3 = 0.f;
                #pragma unroll
                for (int k = 0; k < 16; ++k) {
                    float4 hv = h14[k];
                    a0 = fmaf(wl1[4*k],   hv.x, a0);
                    a1 = fmaf(wl1[4*k+1], hv.y, a1);
                    a2 = fmaf(wl1[4*k+2], hv.z, a2);
                    a3 = fmaf(wl1[4*k+3], hv.w, a3);
                }
                const int srow = l1dir ? (CK - 1 - s) : s;
                const float accL = biasL1 + xg1[i & 1][srow][tid] + ((a0 + a1) + (a2 + a3));
                g1[tid] = ((tid >> 6) == 2) ? tanh_f(accL) : sigm(accL);
                if (tid >= 128 && tid < 192 && u > 0) {   // wave 2: logits of h after step u-1
                    const float hv = h1b[u & 1][tid - 128];
                    float p0 = hv * fw0, p1 = hv * fw1;
                    #pragma unroll
                    for (int d_ = 32; d_ > 0; d_ >>= 1) { p0 += __shfl_xor(p0, d_); p1 += __shfl_xor(p1, d_); }
                    if (tid == 128) {
                        const int tp = l1dir ? (TT - u) : (u - 1);
                        *(float2*)(plog + (((size_t)l1dir * BATCH + b) * TT + tp) * 2) = make_float2(p0, p1);
                    }
                }
            }
            __syncthreads();
            // ======== phase B ========
            if (l1act && tid < 64) {
                const int u = i * CK + s;
                const float iv = g1[tid], fv = g1[64 + tid], gg = g1[128 + tid], ov = g1[192 + tid];
                c1 = fv * c1 + iv * gg;
                h1b[(u + 1) & 1][tid] = ov * tanh_f(c1);
            }
            if (l0act && tid < 128) {
                const float iv = g0[du][eu], fv = g0[du][64 + eu], gg = g0[du][128 + eu], ov = g0[du][192 + eu];
                c0 = fv * c0 + iv * gg;
                const float hv = ov * tanh_f(c0);
                const int orow = du ? (CK - 1 - s) : s;
                h0buf[hbL0][orow][du * 64 + eu] = hv;
                if (s == CK - 1 && (i + 3) < NCH) { h0s[du][eu] = ckh; c0 = ckc; }
                else h0s[du][eu] = hv;
            }
            __syncthreads();
        }
    }
    // final logits (u = TT): h1b[TT&1] = h1b[0]
    if (tid >= 128 && tid < 192) {
        const float hv = h1b[0][tid - 128];
        float p0 = hv * fw0, p1 = hv * fw1;
        #pragma unroll
        for (int d_ = 32; d_ > 0; d_ >>= 1) { p0 += __shfl_xor(p0, d_); p1 += __shfl_xor(p1, d_); }
        if (tid == 128) {
            const int tp = l1dir ? 0 : (TT - 1);
            *(float2*)(plog + (((size_t)l1dir * BATCH + b) * TT + tp) * 2) = make_float2(p0, p1);
        }
    }
}

// ---------------- Kernel C: fused Viterbi (max-plus parallel scan + backtrack) ----------------
__device__ __forceinline__ unsigned long long shfl_u64(unsigned long long v, int src) {
    unsigned int lo = (unsigned int)v, hi = (unsigned int)(v >> 32);
    lo = __shfl(lo, src); hi = __shfl(hi, src);
    return ((unsigned long long)hi << 32) | lo;
}

__global__ __launch_bounds__(64, 1) void viterbi_k(
    const float* __restrict__ plog, const float* __restrict__ fc_b,
    const float* __restrict__ trans, const float* __restrict__ startv,
    const float* __restrict__ endv, int* __restrict__ out)
{
    const int b = blockIdx.x;
    const int lane = threadIdx.x;
    __shared__ __align__(16) float2 e_lds[64][65];   // [t&63][t>>6], padded

    const float fb0 = fc_b[0], fb1 = fc_b[1];
    const float* pf = plog + ((size_t)(0 * BATCH + b) * TT) * 2;
    const float* pb = plog + ((size_t)(1 * BATCH + b) * TT) * 2;
    for (int r = 0; r < 32; ++r) {
        const int i4 = r * 64 + lane;            // covers t = 2*i4, 2*i4+1
        float4 a = ((const float4*)pf)[i4];
        float4 cc = ((const float4*)pb)[i4];
        const int t0 = 2 * i4, t1 = t0 + 1;
        e_lds[t0 & 63][t0 >> 6] = make_float2(a.x + cc.x + fb0, a.y + cc.y + fb1);
        e_lds[t1 & 63][t1 >> 6] = make_float2(a.z + cc.z + fb0, a.w + cc.w + fb1);
    }
    __syncthreads();
    const float tr00 = trans[0], tr01 = trans[1], tr10 = trans[2], tr11 = trans[3];
    const float2 e0 = e_lds[0][0];
    const float s00 = startv[0] + e0.x, s01 = startv[1] + e0.y;   // score at t=0

    const int lo = lane * 64;
    const int hi = (lane == 63) ? (TT - 1) : (lo + 64);
    // pass 1: chunk max-plus matrix A (maps score@lo -> score@hi)
    float a00, a01, a10, a11;
    {
        const float2 ee = e_lds[(lo + 1) & 63][(lo + 1) >> 6];
        a00 = tr00 + ee.x; a01 = tr01 + ee.y; a10 = tr10 + ee.x; a11 = tr11 + ee.y;
    }
    for (int t = lo + 2; t <= hi; ++t) {
        const float2 ee = e_lds[t & 63][t >> 6];
        const float n00 = fmaxf(a00 + tr00, a01 + tr10) + ee.x;
        const float n01 = fmaxf(a00 + tr01, a01 + tr11) + ee.y;
        const float n10 = fmaxf(a10 + tr00, a11 + tr10) + ee.x;
        const float n11 = fmaxf(a10 + tr01, a11 + tr11) + ee.y;
        a00 = n00; a01 = n01; a10 = n10; a11 = n11;
    }
    // inclusive scan: lane i -> A_0 ∘ ... ∘ A_i
    #pragma unroll
    for (int d = 1; d < 64; d <<= 1) {
        const float o00 = __shfl_up(a00, d), o01 = __shfl_up(a01, d);
        const float o10 = __shfl_up(a10, d), o11 = __shfl_up(a11, d);
        if (lane >= d) {
            const float n00 = fmaxf(o00 + a00, o01 + a10);
            const float n01 = fmaxf(o00 + a01, o01 + a11);
            const float n10 = fmaxf(o10 + a00, o11 + a10);
            const float n11 = fmaxf(o10 + a01, o11 + a11);
            a00 = n00; a01 = n01; a10 = n10; a11 = n11;
        }
    }
    // entry score at t=lo
    const float p00 = __shfl_up(a00, 1), p01 = __shfl_up(a01, 1);
    const float p10 = __shfl_up(a10, 1), p11 = __shfl_up(a11, 1);
    float s0, s1;
    if (lane == 0) { s0 = s00; s1 = s01; }
    else { s0 = fmaxf(s00 + p00, s01 + p10); s1 = fmaxf(s00 + p01, s01 + p11); }
    // re-walk, record bp bits
    unsigned long long m0 = 0ull, m1 = 0ull;
    for (int t = lo + 1; t <= hi; ++t) {
        const float2 ee = e_lds[t & 63][t >> 6];
        const float c00 = s0 + tr00, c10 = s1 + tr10;
        const float c01 = s0 + tr01, c11 = s1 + tr11;
        const int bp0 = c10 > c00, bp1 = c11 > c01;   // strict >: first-index tiebreak
        s0 = (bp0 ? c10 : c00) + ee.x;
        s1 = (bp1 ? c11 : c01) + ee.y;
        m0 |= (unsigned long long)bp0 << (t - lo - 1);
        m1 |= (unsigned long long)bp1 << (t - lo - 1);
    }
    int last;
    {
        const int lt = (s1 + endv[1]) > (s0 + endv[0]);
        last = __shfl(lt, 63);
    }
    // chunk map F: tag@hi -> tag@lo
    int f0 = 0, f1 = 1;
    for (int t = hi; t > lo; --t) {
        const int s_ = t - lo - 1;
        f0 = (int)(((f0 ? m1 : m0) >> s_) & 1ull);
        f1 = (int)(((f1 ? m1 : m0) >> s_) & 1ull);
    }
    int mm = f0 | (f1 << 1);
    // suffix scan: G_i = F_i ∘ G_{i+d}
    #pragma unroll
    for (int d = 1; d < 64; d <<= 1) {
        const int mo = __shfl_down(mm, d);
        if (lane + d < 64) {
            const int r0 = (mm >> (mo & 1)) & 1;
            const int r1 = (mm >> ((mo >> 1) & 1)) & 1;
            mm = r0 | (r1 << 1);
        }
    }
    const int gn = __shfl_down(mm, 1);
    int cur = (lane == 63) ? last : ((gn >> last) & 1);   // tag at t=hi
    unsigned long long tagm = 0ull;
    if (lane == 63) tagm |= (unsigned long long)last << 63;
    for (int t = hi; t > lo; --t) {
        const int s_ = t - lo - 1;
        cur = (int)(((cur ? m1 : m0) >> s_) & 1ull);
        tagm |= (unsigned long long)cur << s_;
    }
    int* ob = out + (size_t)b * TT;
    for (int r = 0; r < 64; ++r) {
        const unsigned long long mr = shfl_u64(tagm, r);
        ob[r * 64 + lane] = (int)((mr >> lane) & 1ull);
    }
}

extern "C" void kernel_launch(void* const* d_in, const int* in_sizes, int n_in,
                              void* d_out, int out_size, void* d_ws, size_t ws_size,
                              hipStream_t stream) {
    const float* x      = (const float*)d_in[0];
    const float* w_ih0  = (const float*)d_in[1];
    const float* w_hh0  = (const float*)d_in[2];
    const float* b_ih0  = (const float*)d_in[3];
    const float* b_hh0  = (const float*)d_in[4];
    const float* w_ih1  = (const float*)d_in[5];
    const float* w_hh1  = (const float*)d_in[6];
    const float* b_ih1  = (const float*)d_in[7];
    const float* b_hh1  = (const float*)d_in[8];
    const float* fc_w   = (const float*)d_in[9];
    const float* fc_b   = (const float*)d_in[10];
    const float* trans  = (const float*)d_in[11];
    const float* startv = (const float*)d_in[12];
    const float* endv   = (const float*)d_in[13];

    char* ws = (char*)d_ws;
    const size_t ckpt_bytes = (size_t)2 * BATCH * NSLOT * 128 * 4;   // ~16.9 MB
    float* ckpt = (float*)ws;
    float* plog = (float*)(ws + ckpt_bytes);                          // 8 MB

    lstm_ckpt<<<256, 512, 0, stream>>>(x, w_ih0, w_hh0, b_ih0, b_hh0, ckpt);
    lstm_fused1<<<256, 256, 0, stream>>>(x, w_ih0, w_hh0, b_ih0, b_hh0,
                                         w_ih1, w_hh1, b_ih1, b_hh1,
                                         fc_w, ckpt, plog);
    viterbi_k<<<128, 64, 0, stream>>>(plog, fc_b, trans, startv, endv, (int*)d_out);
}

// Round 7
// 8801.873 us; speedup vs baseline: 1.6159x; 1.6159x over previous
//
#include <hip/hip_runtime.h>

#define TT 4096
#define BATCH 128
#define HID 64
#define CK 16              // chunk size
#define NCH (TT / CK)      // 256 chunks
#define NSLOT (NCH + 1)    // 257 checkpoint slots per (dir,b)

__device__ __forceinline__ float sigm(float x) { return 1.f / (1.f + expf(-x)); }
__device__ __forceinline__ float tanh_f(float x) { float e = expf(2.f * x); return 1.f - 2.f / (e + 1.f); }

// ---------------- Kernel A: layer-0 pass, 2 threads/row, store (h,c) ckpt every CK steps ----------------
__global__ __launch_bounds__(512, 2) void lstm_ckpt(
    const float* __restrict__ x,      // [B][T][2]
    const float* __restrict__ w_ih,   // [2][256][2]
    const float* __restrict__ w_hh,   // [2][256][64]
    const float* __restrict__ b_ih, const float* __restrict__ b_hh,
    float* __restrict__ ckpt)         // [2][B][NSLOT][128] (h:0..63, c:64..127)
{
    const int blk = blockIdx.x;
    const int dir = blk & 1;
    const int b   = blk >> 1;
    const int tid = threadIdx.x;
    const int row = tid >> 1, half = tid & 1;

    __shared__ __align__(16) float xs[TT * 2];
    __shared__ __align__(16) float h_lds[HID];
    __shared__ __align__(16) float g_lds[256];

    {   // stage x[b] (32 KB)
        const float4* src = (const float4*)(x + (size_t)b * TT * 2);
        float4* dst = (float4*)xs;
        for (int rr = tid; rr < 2048; rr += 512) dst[rr] = src[rr];
    }
    const int grow = dir * 256 + row;
    float wv[32];
    {
        const float4* wr = (const float4*)(w_hh + (size_t)grow * 64) + half * 8;
        #pragma unroll
        for (int k = 0; k < 8; ++k) {
            float4 v = wr[k];
            wv[4*k] = v.x; wv[4*k+1] = v.y; wv[4*k+2] = v.z; wv[4*k+3] = v.w;
        }
    }
    const float wx0 = half ? 0.f : w_ih[grow * 2 + 0];
    const float wx1 = half ? 0.f : w_ih[grow * 2 + 1];
    const float bias = half ? 0.f : (b_ih[grow] + b_hh[grow]);
    const int gtype = row >> 6;
    float c = 0.f, hreg = 0.f;
    if (tid < HID) h_lds[tid] = 0.f;
    __syncthreads();

    for (int t = 0; t < TT; ++t) {
        const int tt = dir ? (TT - 1 - t) : t;
        if (tid < HID) {   // state BEFORE processing tt
            const int bnum = dir ? (tt + 1) : tt;
            if ((bnum & (CK - 1)) == 0) {
                float* cp = ckpt + (((size_t)(dir * BATCH + b) * NSLOT + (bnum / CK)) << 7);
                cp[tid] = hreg; cp[HID + tid] = c;
            }
        }
        const float4* h4 = (const float4*)h_lds + half * 8;
        float a0 = 0.f, a1 = 0.f, a2 = 0.f, a3 = 0.f;
        #pragma unroll
        for (int k = 0; k < 8; ++k) {
            float4 hv = h4[k];
            a0 = fmaf(wv[4*k],   hv.x, a0);
            a1 = fmaf(wv[4*k+1], hv.y, a1);
            a2 = fmaf(wv[4*k+2], hv.z, a2);
            a3 = fmaf(wv[4*k+3], hv.w, a3);
        }
        float tot = (a0 + a1) + (a2 + a3);
        tot += __shfl_xor(tot, 1);
        if (half == 0) {
            const float acc = tot + bias + wx0 * xs[tt * 2] + wx1 * xs[tt * 2 + 1];
            g_lds[row] = (gtype == 2) ? tanh_f(acc) : sigm(acc);
        }
        __syncthreads();
        if (tid < HID) {
            const float iv = g_lds[tid], fv = g_lds[64 + tid], gg = g_lds[128 + tid], ov = g_lds[192 + tid];
            c = fv * c + iv * gg;
            hreg = ov * tanh_f(c);
            h_lds[tid] = hreg;
        }
        __syncthreads();
    }
}

// ---------------- Kernel B: fused L1 + GEMM + L0 recompute + logits (512 thr, union wr[96]) ----------
// All 512: L0 row (d0g=tid>>8, j0g=tid&255): 32 w resident + 32 w streamed from wlds.
// tid<256: + L1 row tid (wr[0:64]=wh1, wr[64:96]=wl0-resident).
// tid>=256: + GEMM col tid-256 (wr[0:32]=wl0, wr[32:48]=acc, wr[48:56]=wc pair, wi1 streamed from L2).
// Updates: tid<64 h1; tid<128 L0 state (du,eu); tid in [128,192) logits; [192,200) x prefetch.
__global__ __launch_bounds__(512, 2) void lstm_fused1(
    const float* __restrict__ x,
    const float* __restrict__ w_ih0, const float* __restrict__ w_hh0,
    const float* __restrict__ b_ih0, const float* __restrict__ b_hh0,
    const float* __restrict__ w_ih1, const float* __restrict__ w_hh1,
    const float* __restrict__ b_ih1, const float* __restrict__ b_hh1,
    const float* __restrict__ fc_w,  const float* __restrict__ ckpt,
    float* __restrict__ plog)        // [2][B][T][2]
{
    const int blk = blockIdx.x;
    const int l1dir = blk & 1;
    const int b = blk >> 1;
    const int tid = threadIdx.x;

    __shared__ __align__(16) float wlds[512][36];       // wh0 rows, k in [32,64); 73.7 KB; stride 36 = conflict-rotated
    __shared__ __align__(16) float h0buf[2][CK][128];   // 16 KB
    __shared__ __align__(16) float xg1[2][CK][256];     // 32 KB
    __shared__ __align__(16) float xbuf[2][CK][2];
    __shared__ __align__(16) float g1[256];
    __shared__ __align__(16) float g0[2][256];
    __shared__ __align__(16) float h1b[2][HID];
    __shared__ __align__(16) float h0s[2][HID];

    const bool isL1 = tid < 256;
    const int d0g = tid >> 8;       // L0 dot dir
    const int j0g = tid & 255;      // L0 row
    const int du = tid >> 6;        // L0 update dir (tid<128)
    const int eu = tid & 63;
    const int gcol = tid - 256;     // GEMM col (tid>=256)

    float wr[96];                   // union register file (see role map above)
    float biasL0, wxA0, wxA1, biasL1 = 0.f;
    float fw0 = 0.f, fw1 = 0.f;
    float c1 = 0.f, c0 = 0.f, ckh = 0.f, ckc = 0.f;
    const float4* wip4 = (const float4*)(w_ih1 + (size_t)(l1dir * 256 + (tid & 255)) * 128);

    {   // L0 row: resident k[0,32) + staged k[32,64) into wlds
        const int rowg = d0g * 256 + j0g;
        const float4* wa = (const float4*)(w_hh0 + (size_t)rowg * 64);
        const int base = isL1 ? 64 : 0;
        #pragma unroll
        for (int k = 0; k < 8; ++k) {
            float4 v = wa[k];
            wr[base+4*k] = v.x; wr[base+4*k+1] = v.y; wr[base+4*k+2] = v.z; wr[base+4*k+3] = v.w;
        }
        #pragma unroll
        for (int k = 0; k < 8; ++k)
            *(float4*)&wlds[tid][4*k] = wa[8 + k];
        wxA0 = w_ih0[rowg * 2 + 0]; wxA1 = w_ih0[rowg * 2 + 1];
        biasL0 = b_ih0[rowg] + b_hh0[rowg];
    }
    if (isL1) {
        const int grow = l1dir * 256 + tid;
        const float4* wh = (const float4*)(w_hh1 + (size_t)grow * 64);
        #pragma unroll
        for (int k = 0; k < 16; ++k) {
            float4 v = wh[k];
            wr[4*k] = v.x; wr[4*k+1] = v.y; wr[4*k+2] = v.z; wr[4*k+3] = v.w;
        }
        biasL1 = b_ih1[grow] + b_hh1[grow];
        if (tid >= 128 && tid < 192) {
            fw0 = fc_w[l1dir * 64 + (tid - 128)];
            fw1 = fc_w[128 + l1dir * 64 + (tid - 128)];
        }
    } else {
        #pragma unroll
        for (int k = 0; k < 16; ++k) wr[32 + k] = 0.f;    // acc
        float4 w0 = wip4[0], w1 = wip4[1];
        wr[48] = w0.x; wr[49] = w0.y; wr[50] = w0.z; wr[51] = w0.w;
        wr[52] = w1.x; wr[53] = w1.y; wr[54] = w1.z; wr[55] = w1.w;
    }

    // init: h1 zero, chunk-0 x, chunk-0 ckpt state
    if (tid < HID) { h1b[0][tid] = 0.f; h1b[1][tid] = 0.f; }
    {
        const int ac0 = l1dir ? (NCH - 1) : 0;
        if (tid < 8)
            ((float4*)xbuf[0])[tid] = ((const float4*)(x + ((size_t)b * TT + (size_t)ac0 * CK) * 2))[tid];
        if (tid < 128) {
            const int slot = du ? (ac0 + 1) : ac0;
            const float* cp = ckpt + (((size_t)(du * BATCH + b) * NSLOT + slot) << 7);
            h0s[du][eu] = cp[eu];
            c0 = cp[HID + eu];
        }
    }
    __syncthreads();

    // phase i: L1 consumes chunk i; GEMM builds xg1 for i+1 from h0buf[(i+1)&1];
    //          L0 computes chunk i+2 into h0buf[i&1]; prefetch ckpt/x for chunk i+3.
    for (int i = -2; i < NCH; ++i) {
        const bool l1act = i >= 0;
        const bool gact  = (i + 1 >= 0) && (i + 1 < NCH);
        const bool l0act = (i + 2) < NCH;
        const int hbL0 = i & 1;
        const int hbG  = (i + 1) & 1;
        for (int s = 0; s < CK; ++s) {
            // ======== phase A ========
            if (s == 0 && (i + 3) < NCH) {
                const int acn = l1dir ? (NCH - 1 - (i + 3)) : (i + 3);
                if (tid < 128) {
                    const int slot = du ? (acn + 1) : acn;
                    const float* cp = ckpt + (((size_t)(du * BATCH + b) * NSLOT + slot) << 7);
                    ckh = cp[eu]; ckc = cp[HID + eu];
                }
                if (tid >= 192 && tid < 200)
                    ((float4*)xbuf[(i + 1) & 1])[tid - 192] =
                        ((const float4*)(x + ((size_t)b * TT + (size_t)acn * CK) * 2))[tid - 192];
            }
            if (l0act) {   // L0 dot: resident half + streamed half
                const int orow = d0g ? (CK - 1 - s) : s;
                const float4* h4 = (const float4*)h0s[d0g];
                float a0 = 0.f, a1 = 0.f, a2 = 0.f, a3 = 0.f;
                if (isL1) {
                    #pragma unroll
                    for (int k = 0; k < 8; ++k) {
                        float4 hv = h4[k];
                        a0 = fmaf(wr[64+4*k],   hv.x, a0);
                        a1 = fmaf(wr[64+4*k+1], hv.y, a1);
                        a2 = fmaf(wr[64+4*k+2], hv.z, a2);
                        a3 = fmaf(wr[64+4*k+3], hv.w, a3);
                    }
                } else {
                    #pragma unroll
                    for (int k = 0; k < 8; ++k) {
                        float4 hv = h4[k];
                        a0 = fmaf(wr[4*k],   hv.x, a0);
                        a1 = fmaf(wr[4*k+1], hv.y, a1);
                        a2 = fmaf(wr[4*k+2], hv.z, a2);
                        a3 = fmaf(wr[4*k+3], hv.w, a3);
                    }
                }
                #pragma unroll
                for (int k = 0; k < 8; ++k) {   // streamed k in [32,64)
                    float4 wv = *(const float4*)&wlds[tid][4*k];
                    float4 hv = h4[8 + k];
                    a0 = fmaf(wv.x, hv.x, a0);
                    a1 = fmaf(wv.y, hv.y, a1);
                    a2 = fmaf(wv.z, hv.z, a2);
                    a3 = fmaf(wv.w, hv.w, a3);
                }
                const float xv0 = xbuf[i & 1][orow][0], xv1 = xbuf[i & 1][orow][1];
                const float accA = biasL0 + ((a0 + a1) + (a2 + a3)) + wxA0 * xv0 + wxA1 * xv1;
                g0[d0g][j0g] = ((j0g >> 6) == 2) ? tanh_f(accA) : sigm(accA);
            }
            if (isL1) {
                if (l1act) {
                    const int u = i * CK + s;
                    const float4* h14 = (const float4*)h1b[u & 1];
                    float a0 = 0.f, a1 = 0.f, a2 = 0.f, a3 = 0.f;
                    #pragma unroll
                    for (int k = 0; k < 16; ++k) {
                        float4 hv = h14[k];
                        a0 = fmaf(wr[4*k],   hv.x, a0);
                        a1 = fmaf(wr[4*k+1], hv.y, a1);
                        a2 = fmaf(wr[4*k+2], hv.z, a2);
                        a3 = fmaf(wr[4*k+3], hv.w, a3);
                    }
                    const int srow = l1dir ? (CK - 1 - s) : s;
                    const float accL = biasL1 + xg1[i & 1][srow][tid] + ((a0 + a1) + (a2 + a3));
                    g1[tid] = ((tid >> 6) == 2) ? tanh_f(accL) : sigm(accL);
                    if (tid >= 128 && tid < 192 && u > 0) {   // logits of h after step u-1
                        const float hv = h1b[u & 1][tid - 128];
                        float p0 = hv * fw0, p1 = hv * fw1;
                        #pragma unroll
                        for (int d_ = 32; d_ > 0; d_ >>= 1) { p0 += __shfl_xor(p0, d_); p1 += __shfl_xor(p1, d_); }
                        if (tid == 128) {
                            const int tp = l1dir ? (TT - u) : (u - 1);
                            *(float2*)(plog + (((size_t)l1dir * BATCH + b) * TT + tp) * 2) = make_float2(p0, p1);
                        }
                    }
                }
            } else if (gact) {   // GEMM: k-chunks 2s,2s+1 of chunk i+1
                float4 wn0 = wip4[(2*s + 2) & 31];
                float4 wn1 = wip4[(2*s + 3) & 31];
                const float4* hb = (const float4*)&h0buf[hbG][0][0];
                #pragma unroll
                for (int s2 = 0; s2 < CK; ++s2) {
                    float4 ha = hb[s2 * 32 + 2*s];
                    float4 hc = hb[s2 * 32 + 2*s + 1];
                    float t0 = wr[32 + s2];
                    t0 = fmaf(wr[48], ha.x, t0);
                    t0 = fmaf(wr[49], ha.y, t0);
                    t0 = fmaf(wr[50], ha.z, t0);
                    t0 = fmaf(wr[51], ha.w, t0);
                    t0 = fmaf(wr[52], hc.x, t0);
                    t0 = fmaf(wr[53], hc.y, t0);
                    t0 = fmaf(wr[54], hc.z, t0);
                    t0 = fmaf(wr[55], hc.w, t0);
                    wr[32 + s2] = t0;
                }
                if (s == CK - 1) {
                    #pragma unroll
                    for (int s2 = 0; s2 < CK; ++s2) { xg1[hbG][s2][gcol] = wr[32 + s2]; wr[32 + s2] = 0.f; }
                }
                wr[48] = wn0.x; wr[49] = wn0.y; wr[50] = wn0.z; wr[51] = wn0.w;
                wr[52] = wn1.x; wr[53] = wn1.y; wr[54] = wn1.z; wr[55] = wn1.w;
            }
            __syncthreads();
            // ======== phase B ========
            if (l1act && tid < 64) {
                const int u = i * CK + s;
                const float iv = g1[tid], fv = g1[64 + tid], gg = g1[128 + tid], ov = g1[192 + tid];
                c1 = fv * c1 + iv * gg;
                h1b[(u + 1) & 1][tid] = ov * tanh_f(c1);
            }
            if (l0act && tid < 128) {
                const float iv = g0[du][eu], fv = g0[du][64 + eu], gg = g0[du][128 + eu], ov = g0[du][192 + eu];
                c0 = fv * c0 + iv * gg;
                const float hv = ov * tanh_f(c0);
                const int orow = du ? (CK - 1 - s) : s;
                h0buf[hbL0][orow][du * 64 + eu] = hv;
                if (s == CK - 1 && (i + 3) < NCH) { h0s[du][eu] = ckh; c0 = ckc; }
                else h0s[du][eu] = hv;
            }
            __syncthreads();
        }
    }
    // final logits (u = TT): h1b[TT&1] = h1b[0]
    if (tid >= 128 && tid < 192) {
        const float hv = h1b[0][tid - 128];
        float p0 = hv * fw0, p1 = hv * fw1;
        #pragma unroll
        for (int d_ = 32; d_ > 0; d_ >>= 1) { p0 += __shfl_xor(p0, d_); p1 += __shfl_xor(p1, d_); }
        if (tid == 128) {
            const int tp = l1dir ? 0 : (TT - 1);
            *(float2*)(plog + (((size_t)l1dir * BATCH + b) * TT + tp) * 2) = make_float2(p0, p1);
        }
    }
}

// ---------------- Kernel C: fused Viterbi (max-plus parallel scan + backtrack) ----------------
__device__ __forceinline__ unsigned long long shfl_u64(unsigned long long v, int src) {
    unsigned int lo = (unsigned int)v, hi = (unsigned int)(v >> 32);
    lo = __shfl(lo, src); hi = __shfl(hi, src);
    return ((unsigned long long)hi << 32) | lo;
}

__global__ __launch_bounds__(64, 1) void viterbi_k(
    const float* __restrict__ plog, const float* __restrict__ fc_b,
    const float* __restrict__ trans, const float* __restrict__ startv,
    const float* __restrict__ endv, int* __restrict__ out)
{
    const int b = blockIdx.x;
    const int lane = threadIdx.x;
    __shared__ __align__(16) float2 e_lds[64][65];   // [t&63][t>>6], padded

    const float fb0 = fc_b[0], fb1 = fc_b[1];
    const float* pf = plog + ((size_t)(0 * BATCH + b) * TT) * 2;
    const float* pb = plog + ((size_t)(1 * BATCH + b) * TT) * 2;
    for (int r = 0; r < 32; ++r) {
        const int i4 = r * 64 + lane;            // covers t = 2*i4, 2*i4+1
        float4 a = ((const float4*)pf)[i4];
        float4 cc = ((const float4*)pb)[i4];
        const int t0 = 2 * i4, t1 = t0 + 1;
        e_lds[t0 & 63][t0 >> 6] = make_float2(a.x + cc.x + fb0, a.y + cc.y + fb1);
        e_lds[t1 & 63][t1 >> 6] = make_float2(a.z + cc.z + fb0, a.w + cc.w + fb1);
    }
    __syncthreads();
    const float tr00 = trans[0], tr01 = trans[1], tr10 = trans[2], tr11 = trans[3];
    const float2 e0 = e_lds[0][0];
    const float s00 = startv[0] + e0.x, s01 = startv[1] + e0.y;   // score at t=0

    const int lo = lane * 64;
    const int hi = (lane == 63) ? (TT - 1) : (lo + 64);
    // pass 1: chunk max-plus matrix A (maps score@lo -> score@hi)
    float a00, a01, a10, a11;
    {
        const float2 ee = e_lds[(lo + 1) & 63][(lo + 1) >> 6];
        a00 = tr00 + ee.x; a01 = tr01 + ee.y; a10 = tr10 + ee.x; a11 = tr11 + ee.y;
    }
    for (int t = lo + 2; t <= hi; ++t) {
        const float2 ee = e_lds[t & 63][t >> 6];
        const float n00 = fmaxf(a00 + tr00, a01 + tr10) + ee.x;
        const float n01 = fmaxf(a00 + tr01, a01 + tr11) + ee.y;
        const float n10 = fmaxf(a10 + tr00, a11 + tr10) + ee.x;
        const float n11 = fmaxf(a10 + tr01, a11 + tr11) + ee.y;
        a00 = n00; a01 = n01; a10 = n10; a11 = n11;
    }
    // inclusive scan: lane i -> A_0 ∘ ... ∘ A_i
    #pragma unroll
    for (int d = 1; d < 64; d <<= 1) {
        const float o00 = __shfl_up(a00, d), o01 = __shfl_up(a01, d);
        const float o10 = __shfl_up(a10, d), o11 = __shfl_up(a11, d);
        if (lane >= d) {
            const float n00 = fmaxf(o00 + a00, o01 + a10);
            const float n01 = fmaxf(o00 + a01, o01 + a11);
            const float n10 = fmaxf(o10 + a00, o11 + a10);
            const float n11 = fmaxf(o10 + a01, o11 + a11);
            a00 = n00; a01 = n01; a10 = n10; a11 = n11;
        }
    }
    // entry score at t=lo
    const float p00 = __shfl_up(a00, 1), p01 = __shfl_up(a01, 1);
    const float p10 = __shfl_up(a10, 1), p11 = __shfl_up(a11, 1);
    float s0, s1;
    if (lane == 0) { s0 = s00; s1 = s01; }
    else { s0 = fmaxf(s00 + p00, s01 + p10); s1 = fmaxf(s00 + p01, s01 + p11); }
    // re-walk, record bp bits
    unsigned long long m0 = 0ull, m1 = 0ull;
    for (int t = lo + 1; t <= hi; ++t) {
        const float2 ee = e_lds[t & 63][t >> 6];
        const float c00 = s0 + tr00, c10 = s1 + tr10;
        const float c01 = s0 + tr01, c11 = s1 + tr11;
        const int bp0 = c10 > c00, bp1 = c11 > c01;   // strict >: first-index tiebreak
        s0 = (bp0 ? c10 : c00) + ee.x;
        s1 = (bp1 ? c11 : c01) + ee.y;
        m0 |= (unsigned long long)bp0 << (t - lo - 1);
        m1 |= (unsigned long long)bp1 << (t - lo - 1);
    }
    int last;
    {
        const int lt = (s1 + endv[1]) > (s0 + endv[0]);
        last = __shfl(lt, 63);
    }
    // chunk map F: tag@hi -> tag@lo
    int f0 = 0, f1 = 1;
    for (int t = hi; t > lo; --t) {
        const int s_ = t - lo - 1;
        f0 = (int)(((f0 ? m1 : m0) >> s_) & 1ull);
        f1 = (int)(((f1 ? m1 : m0) >> s_) & 1ull);
    }
    int mm = f0 | (f1 << 1);
    // suffix scan: G_i = F_i ∘ G_{i+d}
    #pragma unroll
    for (int d = 1; d < 64; d <<= 1) {
        const int mo = __shfl_down(mm, d);
        if (lane + d < 64) {
            const int r0 = (mm >> (mo & 1)) & 1;
            const int r1 = (mm >> ((mo >> 1) & 1)) & 1;
            mm = r0 | (r1 << 1);
        }
    }
    const int gn = __shfl_down(mm, 1);
    int cur = (lane == 63) ? last : ((gn >> last) & 1);   // tag at t=hi
    unsigned long long tagm = 0ull;
    if (lane == 63) tagm |= (unsigned long long)last << 63;
    for (int t = hi; t > lo; --t) {
        const int s_ = t - lo - 1;
        cur = (int)(((cur ? m1 : m0) >> s_) & 1ull);
        tagm |= (unsigned long long)cur << s_;
    }
    int* ob = out + (size_t)b * TT;
    for (int r = 0; r < 64; ++r) {
        const unsigned long long mr = shfl_u64(tagm, r);
        ob[r * 64 + lane] = (int)((mr >> lane) & 1ull);
    }
}

extern "C" void kernel_launch(void* const* d_in, const int* in_sizes, int n_in,
                              void* d_out, int out_size, void* d_ws, size_t ws_size,
                              hipStream_t stream) {
    const float* x      = (const float*)d_in[0];
    const float* w_ih0  = (const float*)d_in[1];
    const float* w_hh0  = (const float*)d_in[2];
    const float* b_ih0  = (const float*)d_in[3];
    const float* b_hh0  = (const float*)d_in[4];
    const float* w_ih1  = (const float*)d_in[5];
    const float* w_hh1  = (const float*)d_in[6];
    const float* b_ih1  = (const float*)d_in[7];
    const float* b_hh1  = (const float*)d_in[8];
    const float* fc_w   = (const float*)d_in[9];
    const float* fc_b   = (const float*)d_in[10];
    const float* trans  = (const float*)d_in[11];
    const float* startv = (const float*)d_in[12];
    const float* endv   = (const float*)d_in[13];

    char* ws = (char*)d_ws;
    const size_t ckpt_bytes = (size_t)2 * BATCH * NSLOT * 128 * 4;   // ~33.7 MB
    float* ckpt = (float*)ws;
    float* plog = (float*)(ws + ckpt_bytes);                          // 8 MB

    lstm_ckpt<<<256, 512, 0, stream>>>(x, w_ih0, w_hh0, b_ih0, b_hh0, ckpt);
    lstm_fused1<<<256, 512, 0, stream>>>(x, w_ih0, w_hh0, b_ih0, b_hh0,
                                         w_ih1, w_hh1, b_ih1, b_hh1,
                                         fc_w, ckpt, plog);
    viterbi_k<<<128, 64, 0, stream>>>(plog, fc_b, trans, startv, endv, (int*)d_out);
}

// Round 8
// 8388.582 us; speedup vs baseline: 1.6955x; 1.0493x over previous
//
#include <hip/hip_runtime.h>

#define TT 4096
#define BATCH 128
#define HID 64
#define CK 16              // chunk size
#define NCH (TT / CK)      // 256 chunks
#define NSLOT (NCH + 1)    // 257 checkpoint slots per (dir,b)

__device__ __forceinline__ float sigm(float x) { return 1.f / (1.f + expf(-x)); }
__device__ __forceinline__ float tanh_f(float x) { float e = expf(2.f * x); return 1.f - 2.f / (e + 1.f); }

// ---------------- Kernel A: layer-0 pass, 2 threads/row, store (h,c) ckpt every CK steps ----------------
__global__ __launch_bounds__(512, 2) void lstm_ckpt(
    const float* __restrict__ x,      // [B][T][2]
    const float* __restrict__ w_ih,   // [2][256][2]
    const float* __restrict__ w_hh,   // [2][256][64]
    const float* __restrict__ b_ih, const float* __restrict__ b_hh,
    float* __restrict__ ckpt)         // [2][B][NSLOT][128] (h:0..63, c:64..127)
{
    const int blk = blockIdx.x;
    const int dir = blk & 1;
    const int b   = blk >> 1;
    const int tid = threadIdx.x;
    const int row = tid >> 1, half = tid & 1;

    __shared__ __align__(16) float xs[TT * 2];
    __shared__ __align__(16) float h_lds[HID];
    __shared__ __align__(16) float g_lds[256];

    {   // stage x[b] (32 KB)
        const float4* src = (const float4*)(x + (size_t)b * TT * 2);
        float4* dst = (float4*)xs;
        for (int rr = tid; rr < 2048; rr += 512) dst[rr] = src[rr];
    }
    const int grow = dir * 256 + row;
    float wv[32];
    {
        const float4* wr = (const float4*)(w_hh + (size_t)grow * 64) + half * 8;
        #pragma unroll
        for (int k = 0; k < 8; ++k) {
            float4 v = wr[k];
            wv[4*k] = v.x; wv[4*k+1] = v.y; wv[4*k+2] = v.z; wv[4*k+3] = v.w;
        }
    }
    const float wx0 = half ? 0.f : w_ih[grow * 2 + 0];
    const float wx1 = half ? 0.f : w_ih[grow * 2 + 1];
    const float bias = half ? 0.f : (b_ih[grow] + b_hh[grow]);
    const int gtype = row >> 6;
    float c = 0.f, hreg = 0.f;
    if (tid < HID) h_lds[tid] = 0.f;
    __syncthreads();

    for (int t = 0; t < TT; ++t) {
        const int tt = dir ? (TT - 1 - t) : t;
        if (tid < HID) {   // state BEFORE processing tt
            const int bnum = dir ? (tt + 1) : tt;
            if ((bnum & (CK - 1)) == 0) {
                float* cp = ckpt + (((size_t)(dir * BATCH + b) * NSLOT + (bnum / CK)) << 7);
                cp[tid] = hreg; cp[HID + tid] = c;
            }
        }
        const float4* h4 = (const float4*)h_lds + half * 8;
        float a0 = 0.f, a1 = 0.f, a2 = 0.f, a3 = 0.f;
        #pragma unroll
        for (int k = 0; k < 8; ++k) {
            float4 hv = h4[k];
            a0 = fmaf(wv[4*k],   hv.x, a0);
            a1 = fmaf(wv[4*k+1], hv.y, a1);
            a2 = fmaf(wv[4*k+2], hv.z, a2);
            a3 = fmaf(wv[4*k+3], hv.w, a3);
        }
        float tot = (a0 + a1) + (a2 + a3);
        tot += __shfl_xor(tot, 1);
        if (half == 0) {
            const float acc = tot + bias + wx0 * xs[tt * 2] + wx1 * xs[tt * 2 + 1];
            g_lds[row] = (gtype == 2) ? tanh_f(acc) : sigm(acc);
        }
        __syncthreads();
        if (tid < HID) {
            const float iv = g_lds[tid], fv = g_lds[64 + tid], gg = g_lds[128 + tid], ov = g_lds[192 + tid];
            c = fv * c + iv * gg;
            hreg = ov * tanh_f(c);
            h_lds[tid] = hreg;
        }
        __syncthreads();
    }
}

// ---------------- Kernel B: fused L1 + GEMM + L0 recompute + logits; 512 thr, all-register weights ----
// Every thread: L0 row (d0g=tid>>8, j0g=tid&255) with wl0[64].
// Every thread: L1 row r1=tid>>1, half hf=tid&1 with wl1[32] (shfl_xor pair combine).
// Every thread: GEMM col cg=tid>>1, k-half hf: acc[16], streamed wi1 float4 (partials merged via xg1).
// Updates: tid<64 h1; tid in [64,192) L0 states; [192,256) logits; [256,264) x prefetch.
// LDS ~53 KB -> 2 blocks/CU at __launch_bounds__(512,2) (16 waves: TLP hides barrier stalls).
__global__ __launch_bounds__(512, 2) void lstm_fused1(
    const float* __restrict__ x,
    const float* __restrict__ w_ih0, const float* __restrict__ w_hh0,
    const float* __restrict__ b_ih0, const float* __restrict__ b_hh0,
    const float* __restrict__ w_ih1, const float* __restrict__ w_hh1,
    const float* __restrict__ b_ih1, const float* __restrict__ b_hh1,
    const float* __restrict__ fc_w,  const float* __restrict__ ckpt,
    float* __restrict__ plog)        // [2][B][T][2]
{
    const int blk = blockIdx.x;
    const int l1dir = blk & 1;
    const int b = blk >> 1;
    const int tid = threadIdx.x;

    __shared__ __align__(16) float h0buf[2][CK][128];   // 16 KB
    __shared__ __align__(16) float xg1[2][CK][256];     // 32 KB
    __shared__ __align__(16) float xbuf[2][CK][2];      // 256 B
    __shared__ __align__(16) float g1[256];
    __shared__ __align__(16) float g0[2][256];
    __shared__ __align__(16) float h1b[2][HID];
    __shared__ __align__(16) float h0s[2][HID];

    const int d0g = tid >> 8;        // L0 dir (wave-uniform)
    const int j0g = tid & 255;       // L0 row
    const int r1  = tid >> 1;        // L1 row / GEMM col
    const int hf  = tid & 1;         // L1 half / GEMM k-half
    const bool updL0 = (tid >= 64) && (tid < 192);
    const int du = (tid - 64) >> 6;  // L0 update dir (valid when updL0)
    const int eu = tid & 63;
    const bool logitT = (tid >= 192) && (tid < 256);

    float wl0[64];                   // w_hh0 row (d0g, j0g)
    float wl1[32];                   // w_hh1 row r1, half hf
    float acc[CK];                   // GEMM accumulators (k-half partial)
    float4 wc;                       // streamed wi1 float4 (current step)
    float wx0, wx1, bias0, bias1;
    float fw0 = 0.f, fw1 = 0.f;
    float c1 = 0.f, c0 = 0.f, ckh = 0.f, ckc = 0.f;
    const float4* wip4 = (const float4*)(w_ih1 + (size_t)(l1dir * 256 + r1) * 128);

    {   // L0 weights
        const int rowg = d0g * 256 + j0g;
        const float4* wa = (const float4*)(w_hh0 + (size_t)rowg * 64);
        #pragma unroll
        for (int k = 0; k < 16; ++k) {
            float4 v = wa[k];
            wl0[4*k] = v.x; wl0[4*k+1] = v.y; wl0[4*k+2] = v.z; wl0[4*k+3] = v.w;
        }
        wx0 = w_ih0[rowg * 2 + 0]; wx1 = w_ih0[rowg * 2 + 1];
        bias0 = b_ih0[rowg] + b_hh0[rowg];
    }
    {   // L1 half-row weights
        const int grow1 = l1dir * 256 + r1;
        const float4* wh = (const float4*)(w_hh1 + (size_t)grow1 * 64) + hf * 8;
        #pragma unroll
        for (int k = 0; k < 8; ++k) {
            float4 v = wh[k];
            wl1[4*k] = v.x; wl1[4*k+1] = v.y; wl1[4*k+2] = v.z; wl1[4*k+3] = v.w;
        }
        bias1 = b_ih1[grow1] + b_hh1[grow1];
    }
    #pragma unroll
    for (int k = 0; k < CK; ++k) acc[k] = 0.f;
    wc = wip4[hf];                   // step 0 k-half
    if (logitT) {
        fw0 = fc_w[l1dir * 64 + (tid - 192)];
        fw1 = fc_w[128 + l1dir * 64 + (tid - 192)];
    }

    // init: h1 zero, chunk-0 x, chunk-0 ckpt state
    if (tid < HID) { h1b[0][tid] = 0.f; h1b[1][tid] = 0.f; }
    {
        const int ac0 = l1dir ? (NCH - 1) : 0;
        if (tid >= 256 && tid < 264)
            ((float4*)xbuf[0])[tid - 256] = ((const float4*)(x + ((size_t)b * TT + (size_t)ac0 * CK) * 2))[tid - 256];
        if (updL0) {
            const int slot = du ? (ac0 + 1) : ac0;
            const float* cp = ckpt + (((size_t)(du * BATCH + b) * NSLOT + slot) << 7);
            h0s[du][eu] = cp[eu];
            c0 = cp[HID + eu];
        }
    }
    __syncthreads();

    // phase i: L1 consumes chunk i; GEMM builds xg1 for i+1 from h0buf[(i+1)&1];
    //          L0 computes chunk i+2 into h0buf[i&1]; prefetch ckpt/x for chunk i+3.
    for (int i = -2; i < NCH; ++i) {
        const bool l1act = i >= 0;
        const bool gact  = (i + 1 >= 0) && (i + 1 < NCH);
        const bool l0act = (i + 2) < NCH;
        const int hbL0 = i & 1;
        const int hbG  = (i + 1) & 1;
        for (int s = 0; s < CK; ++s) {
            // ======== phase A ========
            if (s == 0 && (i + 3) < NCH) {
                const int acn = l1dir ? (NCH - 1 - (i + 3)) : (i + 3);
                if (updL0) {
                    const int slot = du ? (acn + 1) : acn;
                    const float* cp = ckpt + (((size_t)(du * BATCH + b) * NSLOT + slot) << 7);
                    ckh = cp[eu]; ckc = cp[HID + eu];
                }
                if (tid >= 256 && tid < 264)
                    ((float4*)xbuf[(i + 1) & 1])[tid - 256] =
                        ((const float4*)(x + ((size_t)b * TT + (size_t)acn * CK) * 2))[tid - 256];
            }
            float4 wn = wip4[2 * ((s + 1) & (CK - 1)) + hf];   // prefetch next step's wi1 slice
            if (gact) {   // GEMM: k-slice (8s + 4hf .. +4) across all CK steps of chunk i+1
                const int k0 = 8 * s + 4 * hf;
                #pragma unroll
                for (int s2 = 0; s2 < CK; ++s2) {
                    float4 hv = *(const float4*)&h0buf[hbG][s2][k0];
                    acc[s2] = fmaf(wc.w, hv.w, fmaf(wc.z, hv.z, fmaf(wc.y, hv.y, fmaf(wc.x, hv.x, acc[s2]))));
                }
                if (s == CK - 1 && hf == 0) {
                    #pragma unroll
                    for (int s2 = 0; s2 < CK; ++s2) xg1[hbG][s2][r1] = acc[s2];
                }
            }
            wc = wn;
            if (l0act) {   // L0 dot (full 64, register weights)
                const int orow = d0g ? (CK - 1 - s) : s;
                const float4* h4 = (const float4*)h0s[d0g];
                float a0 = 0.f, a1 = 0.f, a2 = 0.f, a3 = 0.f;
                #pragma unroll
                for (int k = 0; k < 16; ++k) {
                    float4 hv = h4[k];
                    a0 = fmaf(wl0[4*k],   hv.x, a0);
                    a1 = fmaf(wl0[4*k+1], hv.y, a1);
                    a2 = fmaf(wl0[4*k+2], hv.z, a2);
                    a3 = fmaf(wl0[4*k+3], hv.w, a3);
                }
                const float accA = bias0 + ((a0 + a1) + (a2 + a3))
                                 + wx0 * xbuf[i & 1][orow][0] + wx1 * xbuf[i & 1][orow][1];
                g0[d0g][j0g] = ((j0g >> 6) == 2) ? tanh_f(accA) : sigm(accA);
            }
            if (l1act) {   // L1 dot (2 threads/row) + logits
                const int u = i * CK + s;
                const float4* h14 = (const float4*)h1b[u & 1] + hf * 8;
                float a0 = 0.f, a1 = 0.f, a2 = 0.f, a3 = 0.f;
                #pragma unroll
                for (int k = 0; k < 8; ++k) {
                    float4 hv = h14[k];
                    a0 = fmaf(wl1[4*k],   hv.x, a0);
                    a1 = fmaf(wl1[4*k+1], hv.y, a1);
                    a2 = fmaf(wl1[4*k+2], hv.z, a2);
                    a3 = fmaf(wl1[4*k+3], hv.w, a3);
                }
                float tot = (a0 + a1) + (a2 + a3);
                tot += __shfl_xor(tot, 1);
                if (hf == 0) {
                    const int srow = l1dir ? (CK - 1 - s) : s;
                    const float accL = bias1 + xg1[i & 1][srow][r1] + tot;
                    g1[r1] = ((r1 >> 6) == 2) ? tanh_f(accL) : sigm(accL);
                }
                if (logitT && u > 0) {   // wave 3: logits of h after step u-1
                    const float hv = h1b[u & 1][tid - 192];
                    float p0 = hv * fw0, p1 = hv * fw1;
                    #pragma unroll
                    for (int d_ = 32; d_ > 0; d_ >>= 1) { p0 += __shfl_xor(p0, d_); p1 += __shfl_xor(p1, d_); }
                    if (tid == 192) {
                        const int tp = l1dir ? (TT - u) : (u - 1);
                        *(float2*)(plog + (((size_t)l1dir * BATCH + b) * TT + tp) * 2) = make_float2(p0, p1);
                    }
                }
            }
            __syncthreads();
            // ======== phase B ========
            if (l1act && tid < 64) {
                const int u = i * CK + s;
                const float iv = g1[tid], fv = g1[64 + tid], gg = g1[128 + tid], ov = g1[192 + tid];
                c1 = fv * c1 + iv * gg;
                h1b[(u + 1) & 1][tid] = ov * tanh_f(c1);
            }
            if (l0act && updL0) {
                const float iv = g0[du][eu], fv = g0[du][64 + eu], gg = g0[du][128 + eu], ov = g0[du][192 + eu];
                c0 = fv * c0 + iv * gg;
                const float hv = ov * tanh_f(c0);
                const int orow = du ? (CK - 1 - s) : s;
                h0buf[hbL0][orow][du * 64 + eu] = hv;
                if (s == CK - 1 && (i + 3) < NCH) { h0s[du][eu] = ckh; c0 = ckc; }
                else h0s[du][eu] = hv;
            }
            if (gact && s == CK - 1) {   // merge GEMM k-half partials; reset accs
                if (hf == 1) {
                    #pragma unroll
                    for (int s2 = 0; s2 < CK; ++s2) xg1[hbG][s2][r1] += acc[s2];
                }
                #pragma unroll
                for (int s2 = 0; s2 < CK; ++s2) acc[s2] = 0.f;
            }
            __syncthreads();
        }
    }
    // final logits (u = TT): h1b[TT&1] = h1b[0]
    if (logitT) {
        const float hv = h1b[0][tid - 192];
        float p0 = hv * fw0, p1 = hv * fw1;
        #pragma unroll
        for (int d_ = 32; d_ > 0; d_ >>= 1) { p0 += __shfl_xor(p0, d_); p1 += __shfl_xor(p1, d_); }
        if (tid == 192) {
            const int tp = l1dir ? 0 : (TT - 1);
            *(float2*)(plog + (((size_t)l1dir * BATCH + b) * TT + tp) * 2) = make_float2(p0, p1);
        }
    }
}

// ---------------- Kernel C: fused Viterbi (max-plus parallel scan + backtrack) ----------------
__device__ __forceinline__ unsigned long long shfl_u64(unsigned long long v, int src) {
    unsigned int lo = (unsigned int)v, hi = (unsigned int)(v >> 32);
    lo = __shfl(lo, src); hi = __shfl(hi, src);
    return ((unsigned long long)hi << 32) | lo;
}

__global__ __launch_bounds__(64, 1) void viterbi_k(
    const float* __restrict__ plog, const float* __restrict__ fc_b,
    const float* __restrict__ trans, const float* __restrict__ startv,
    const float* __restrict__ endv, int* __restrict__ out)
{
    const int b = blockIdx.x;
    const int lane = threadIdx.x;
    __shared__ __align__(16) float2 e_lds[64][65];   // [t&63][t>>6], padded

    const float fb0 = fc_b[0], fb1 = fc_b[1];
    const float* pf = plog + ((size_t)(0 * BATCH + b) * TT) * 2;
    const float* pb = plog + ((size_t)(1 * BATCH + b) * TT) * 2;
    for (int r = 0; r < 32; ++r) {
        const int i4 = r * 64 + lane;            // covers t = 2*i4, 2*i4+1
        float4 a = ((const float4*)pf)[i4];
        float4 cc = ((const float4*)pb)[i4];
        const int t0 = 2 * i4, t1 = t0 + 1;
        e_lds[t0 & 63][t0 >> 6] = make_float2(a.x + cc.x + fb0, a.y + cc.y + fb1);
        e_lds[t1 & 63][t1 >> 6] = make_float2(a.z + cc.z + fb0, a.w + cc.w + fb1);
    }
    __syncthreads();
    const float tr00 = trans[0], tr01 = trans[1], tr10 = trans[2], tr11 = trans[3];
    const float2 e0 = e_lds[0][0];
    const float s00 = startv[0] + e0.x, s01 = startv[1] + e0.y;   // score at t=0

    const int lo = lane * 64;
    const int hi = (lane == 63) ? (TT - 1) : (lo + 64);
    // pass 1: chunk max-plus matrix A (maps score@lo -> score@hi)
    float a00, a01, a10, a11;
    {
        const float2 ee = e_lds[(lo + 1) & 63][(lo + 1) >> 6];
        a00 = tr00 + ee.x; a01 = tr01 + ee.y; a10 = tr10 + ee.x; a11 = tr11 + ee.y;
    }
    for (int t = lo + 2; t <= hi; ++t) {
        const float2 ee = e_lds[t & 63][t >> 6];
        const float n00 = fmaxf(a00 + tr00, a01 + tr10) + ee.x;
        const float n01 = fmaxf(a00 + tr01, a01 + tr11) + ee.y;
        const float n10 = fmaxf(a10 + tr00, a11 + tr10) + ee.x;
        const float n11 = fmaxf(a10 + tr01, a11 + tr11) + ee.y;
        a00 = n00; a01 = n01; a10 = n10; a11 = n11;
    }
    // inclusive scan: lane i -> A_0 ∘ ... ∘ A_i
    #pragma unroll
    for (int d = 1; d < 64; d <<= 1) {
        const float o00 = __shfl_up(a00, d), o01 = __shfl_up(a01, d);
        const float o10 = __shfl_up(a10, d), o11 = __shfl_up(a11, d);
        if (lane >= d) {
            const float n00 = fmaxf(o00 + a00, o01 + a10);
            const float n01 = fmaxf(o00 + a01, o01 + a11);
            const float n10 = fmaxf(o10 + a00, o11 + a10);
            const float n11 = fmaxf(o10 + a01, o11 + a11);
            a00 = n00; a01 = n01; a10 = n10; a11 = n11;
        }
    }
    // entry score at t=lo
    const float p00 = __shfl_up(a00, 1), p01 = __shfl_up(a01, 1);
    const float p10 = __shfl_up(a10, 1), p11 = __shfl_up(a11, 1);
    float s0, s1;
    if (lane == 0) { s0 = s00; s1 = s01; }
    else { s0 = fmaxf(s00 + p00, s01 + p10); s1 = fmaxf(s00 + p01, s01 + p11); }
    // re-walk, record bp bits
    unsigned long long m0 = 0ull, m1 = 0ull;
    for (int t = lo + 1; t <= hi; ++t) {
        const float2 ee = e_lds[t & 63][t >> 6];
        const float c00 = s0 + tr00, c10 = s1 + tr10;
        const float c01 = s0 + tr01, c11 = s1 + tr11;
        const int bp0 = c10 > c00, bp1 = c11 > c01;   // strict >: first-index tiebreak
        s0 = (bp0 ? c10 : c00) + ee.x;
        s1 = (bp1 ? c11 : c01) + ee.y;
        m0 |= (unsigned long long)bp0 << (t - lo - 1);
        m1 |= (unsigned long long)bp1 << (t - lo - 1);
    }
    int last;
    {
        const int lt = (s1 + endv[1]) > (s0 + endv[0]);
        last = __shfl(lt, 63);
    }
    // chunk map F: tag@hi -> tag@lo
    int f0 = 0, f1 = 1;
    for (int t = hi; t > lo; --t) {
        const int s_ = t - lo - 1;
        f0 = (int)(((f0 ? m1 : m0) >> s_) & 1ull);
        f1 = (int)(((f1 ? m1 : m0) >> s_) & 1ull);
    }
    int mm = f0 | (f1 << 1);
    // suffix scan: G_i = F_i ∘ G_{i+d}
    #pragma unroll
    for (int d = 1; d < 64; d <<= 1) {
        const int mo = __shfl_down(mm, d);
        if (lane + d < 64) {
            const int r0 = (mm >> (mo & 1)) & 1;
            const int r1_ = (mm >> ((mo >> 1) & 1)) & 1;
            mm = r0 | (r1_ << 1);
        }
    }
    const int gn = __shfl_down(mm, 1);
    int cur = (lane == 63) ? last : ((gn >> last) & 1);   // tag at t=hi
    unsigned long long tagm = 0ull;
    if (lane == 63) tagm |= (unsigned long long)last << 63;
    for (int t = hi; t > lo; --t) {
        const int s_ = t - lo - 1;
        cur = (int)(((cur ? m1 : m0) >> s_) & 1ull);
        tagm |= (unsigned long long)cur << s_;
    }
    int* ob = out + (size_t)b * TT;
    for (int r = 0; r < 64; ++r) {
        const unsigned long long mr = shfl_u64(tagm, r);
        ob[r * 64 + lane] = (int)((mr >> lane) & 1ull);
    }
}

extern "C" void kernel_launch(void* const* d_in, const int* in_sizes, int n_in,
                              void* d_out, int out_size, void* d_ws, size_t ws_size,
                              hipStream_t stream) {
    const float* x      = (const float*)d_in[0];
    const float* w_ih0  = (const float*)d_in[1];
    const float* w_hh0  = (const float*)d_in[2];
    const float* b_ih0  = (const float*)d_in[3];
    const float* b_hh0  = (const float*)d_in[4];
    const float* w_ih1  = (const float*)d_in[5];
    const float* w_hh1  = (const float*)d_in[6];
    const float* b_ih1  = (const float*)d_in[7];
    const float* b_hh1  = (const float*)d_in[8];
    const float* fc_w   = (const float*)d_in[9];
    const float* fc_b   = (const float*)d_in[10];
    const float* trans  = (const float*)d_in[11];
    const float* startv = (const float*)d_in[12];
    const float* endv   = (const float*)d_in[13];

    char* ws = (char*)d_ws;
    const size_t ckpt_bytes = (size_t)2 * BATCH * NSLOT * 128 * 4;   // ~33.7 MB
    float* ckpt = (float*)ws;
    float* plog = (float*)(ws + ckpt_bytes);                          // 8 MB

    lstm_ckpt<<<256, 512, 0, stream>>>(x, w_ih0, w_hh0, b_ih0, b_hh0, ckpt);
    lstm_fused1<<<256, 512, 0, stream>>>(x, w_ih0, w_hh0, b_ih0, b_hh0,
                                         w_ih1, w_hh1, b_ih1, b_hh1,
                                         fc_w, ckpt, plog);
    viterbi_k<<<128, 64, 0, stream>>>(plog, fc_b, trans, startv, endv, (int*)d_out);
}